// Round 8
// baseline (201.438 us; speedup 1.0000x reference)
//
#include <hip/hip_runtime.h>
#include <math.h>

#define BB 16
#define SS 2048
#define DD 768
#define NROW (BB * SS) // 32768
#define NSLICE 16      // o-dimension split for weight fold

typedef float nfloat4 __attribute__((ext_vector_type(4))); // native vec for nontemporal builtins

// ws layout (float-granular offsets)
#define PART_OFF  0                        // NSLICE*2304 floats: partial w3 sums
#define W3_OFF    (PART_OFF + NSLICE*2304) // 2304 floats: w3[k][i]
#define BIAS_OFF  (W3_OFF + 2304)          // 1 float (+pad)
#define E0_OFF    (BIAS_OFF + 64)          // NROW floats each
#define E1_OFF    (E0_OFF + NROW)
#define E2_OFF    (E1_OFF + NROW)
#define WPK_OFF   (E2_OFF + NROW)          // 2*NROW floats: (wcur, wnext) pairs
#define FT_OFF    (WPK_OFF + 2*NROW)       // NROW ints: fire time of output row j
#define LEN_OFF   (FT_OFF + NROW)          // BB ints

// K1a: partial fold over an o-slice. grid = NSLICE*9 blocks.
__global__ __launch_bounds__(256) void k1a_fold_part(
    const float* __restrict__ conv_w, const float* __restrict__ lin_w,
    float* __restrict__ ws) {
  int tid = threadIdx.x;
  int slice = blockIdx.x / 9, cb = blockIdx.x % 9;
  int c = cb * 256 + tid; // c in [0,2304)
  int o0 = slice * (DD / NSLICE);
  float acc = 0.f;
#pragma unroll 4
  for (int oo = 0; oo < DD / NSLICE; ++oo) {
    int o = o0 + oo;
    acc = fmaf(lin_w[o], conv_w[(size_t)o * 2304 + c], acc); // coalesced over c
  }
  ws[PART_OFF + slice * 2304 + c] = acc;
}

// K1r: reduce partials -> w3[k*DD+i]; block 9 computes bias_eff.
__global__ __launch_bounds__(256) void k1r_fold_reduce(
    const float* __restrict__ conv_b, const float* __restrict__ lin_w,
    const float* __restrict__ lin_b, float* __restrict__ ws) {
  __shared__ float red[256];
  int tid = threadIdx.x;
  if (blockIdx.x < 9) {
    int c = blockIdx.x * 256 + tid;
    float acc = 0.f;
#pragma unroll
    for (int s = 0; s < NSLICE; ++s) acc += ws[PART_OFF + s * 2304 + c];
    int i = c / 3, k = c % 3;
    ws[W3_OFF + k * DD + i] = acc;
  } else {
    float p = 0.f;
    for (int o = tid; o < DD; o += 256) p = fmaf(lin_w[o], conv_b[o], p);
    red[tid] = p;
    __syncthreads();
    for (int off = 128; off > 0; off >>= 1) {
      if (tid < off) red[tid] += red[tid + off];
      __syncthreads();
    }
    if (tid == 0) ws[BIAS_OFF] = red[0] + lin_b[0];
  }
}

// K2a: e_k[row] = sum_i w3[k][i]*x[row][i] for rows s <= len[b].
// TWO rows per wave, 8 rows/block (4096 blocks). w3 (9 KB) read straight from
// global — L1-resident after first touch per CU; no LDS fill, no barrier.
__global__ __launch_bounds__(256) void k2a_dots(
    const float* __restrict__ x, const float* __restrict__ ws,
    const int* __restrict__ lens,
    float* __restrict__ e0, float* __restrict__ e1, float* __restrict__ e2) {
  const int tid = threadIdx.x, wave = tid >> 6, lane = tid & 63;
  const int blk = blockIdx.x;
  const int b = blk >> 8;          // 256 blocks per batch
  const int len = lens[b];
  const int baseS = (blk & 255) * 8;
  if (baseS > len) return;         // block-uniform exit
  const int s0 = baseS + wave * 2; // rows s0, s0+1
  if (s0 > len) return;            // wave-uniform
  const bool r1 = (s0 + 1 <= len);
  const int row0 = b * SS + s0;
  const float4* xr0 = (const float4*)(x + (size_t)row0 * DD);
  const float4* xr1 = xr0 + DD / 4;
  const float4* w0p = (const float4*)(ws + W3_OFF);
  const float4* w1p = (const float4*)(ws + W3_OFF + DD);
  const float4* w2p = (const float4*)(ws + W3_OFF + 2 * DD);
  float a00 = 0.f, a01 = 0.f, a02 = 0.f;
  float a10 = 0.f, a11 = 0.f, a12 = 0.f;
#pragma unroll
  for (int q = 0; q < 3; ++q) {
    int f = lane + q * 64;         // float4 index, 192 per row
    float4 w0 = w0p[f], w1 = w1p[f], w2 = w2p[f];
    float4 xv = xr0[f];
    a00 += w0.x * xv.x + w0.y * xv.y + w0.z * xv.z + w0.w * xv.w;
    a01 += w1.x * xv.x + w1.y * xv.y + w1.z * xv.z + w1.w * xv.w;
    a02 += w2.x * xv.x + w2.y * xv.y + w2.z * xv.z + w2.w * xv.w;
    if (r1) {
      float4 yv = xr1[f];
      a10 += w0.x * yv.x + w0.y * yv.y + w0.z * yv.z + w0.w * yv.w;
      a11 += w1.x * yv.x + w1.y * yv.y + w1.z * yv.z + w1.w * yv.w;
      a12 += w2.x * yv.x + w2.y * yv.y + w2.z * yv.z + w2.w * yv.w;
    }
  }
#pragma unroll
  for (int m = 1; m < 64; m <<= 1) {
    a00 += __shfl_xor(a00, m); a01 += __shfl_xor(a01, m); a02 += __shfl_xor(a02, m);
    a10 += __shfl_xor(a10, m); a11 += __shfl_xor(a11, m); a12 += __shfl_xor(a12, m);
  }
  if (lane == 0) {
    e0[row0] = a00; e1[row0] = a01; e2[row0] = a02;
    if (r1) { e0[row0 + 1] = a10; e1[row0 + 1] = a11; e2[row0 + 1] = a12; }
  }
}

// K3: fused alpha (stencil+sigmoid+mask) + per-batch prefix scan (wave shuffles,
// single barrier). aacc_t = P_t - floor(P_t); fire where floor increments.
__global__ __launch_bounds__(256) void k3_scan(
    const float* __restrict__ ws_ro, const int* __restrict__ lens,
    float2* __restrict__ wpk_g, int* __restrict__ ft_g,
    int* __restrict__ lenws, float* __restrict__ out_len) {
  __shared__ double wtot[4];
  const int b = blockIdx.x, tid = threadIdx.x;
  const int wave = tid >> 6, lane = tid & 63;
  const float* e0 = ws_ro + E0_OFF + b * SS;
  const float* e1 = ws_ro + E1_OFF + b * SS;
  const float* e2 = ws_ro + E2_OFF + b * SS;
  float2* wpk = wpk_g + b * SS;
  int* ft = ft_g + b * SS;
  const float bias = ws_ro[BIAS_OFF];
  const int len = lens[b];
  const int t0 = tid * 8;
  float a[8];
  double incl[8];
  double run = 0.0;
#pragma unroll
  for (int e = 0; e < 8; ++e) {
    int t = t0 + e;
    float av = 0.f;
    if (t < len) {
      float z = bias + e1[t];
      if (t > 0) z += e0[t - 1];
      if (t < SS - 1) z += e2[t + 1]; // SAME-pad: no x[s+1] term at s = S-1
      av = 1.f / (1.f + expf(-z));
    }
    a[e] = av;
    run += (double)av;
    incl[e] = run;
  }
  double v = run; // inclusive wave-scan of per-thread totals
#pragma unroll
  for (int m = 1; m < 64; m <<= 1) {
    double o = __shfl_up(v, m);
    if (lane >= m) v += o;
  }
  if (lane == 63) wtot[wave] = v;
  __syncthreads();
  double woff = 0.0;
  for (int w = 0; w < wave; ++w) woff += wtot[w];
  double excl = woff + v - run;
  double Pprev = excl;
  int Fprev = (int)floor(excl);
#pragma unroll
  for (int e = 0; e < 8; ++e) {
    int t = t0 + e;
    double P = excl + incl[e];
    int F = (int)floor(P);
    bool fire = (F > Fprev); // alpha in [0,1) => F steps by at most 1
    float2 wv;
    wv.x = fire ? (float)((double)F - Pprev) : a[e]; // a1 on fire, alpha otherwise
    wv.y = fire ? (float)(P - (double)F) : 0.f;      // a2 carried to next segment
    wpk[t] = wv;
    if (fire) ft[F - 1] = t;
    Pprev = P;
    Fprev = F;
  }
  if (tid == 255) {
    int L = (int)floor(woff + v);
    lenws[b] = L;
    out_len[b] = (float)L;
  }
}

// K4: TWO consecutive output rows (j0, j0+1) per wave — the shared boundary
// encoder row x[ft[j0]] is loaded once for both accumulators. Segments:
// row j = wnext[ft[j-1]]*x[ft[j-1]] + sum_(ft[j-1],ft[j]) wcur*x + wcur[ft[j]]*x[ft[j]].
// All branches wave-uniform. j>=L rows -> zeros. NT stores keep L2/L3 for the gather.
__global__ __launch_bounds__(256) void k4_emit(
    const float* __restrict__ x, const float* __restrict__ ws_ro,
    float* __restrict__ out) {
  const int tid = threadIdx.x, wave = tid >> 6, lane = tid & 63;
  const int pair = blockIdx.x * 4 + wave; // 16384 pairs
  const int b = pair >> 10;               // 1024 pairs per batch
  const int j0 = (pair & 1023) * 2;
  nfloat4* orow0 = (nfloat4*)(out + ((size_t)b * SS + j0) * DD);
  nfloat4* orow1 = orow0 + DD / 4;
  const int L = ((const int*)ws_ro)[LEN_OFF + b];
  nfloat4 z = {0.f, 0.f, 0.f, 0.f};
  if (j0 >= L) {
    __builtin_nontemporal_store(z, orow0 + lane);
    __builtin_nontemporal_store(z, orow0 + lane + 64);
    __builtin_nontemporal_store(z, orow0 + lane + 128);
    __builtin_nontemporal_store(z, orow1 + lane);
    __builtin_nontemporal_store(z, orow1 + lane + 64);
    __builtin_nontemporal_store(z, orow1 + lane + 128);
    return;
  }
  const int* ft = ((const int*)ws_ro) + FT_OFF + b * SS;
  const float2* wpk = (const float2*)(ws_ro + WPK_OFF) + b * SS;
  const int start0 = (j0 == 0) ? 0 : ft[j0 - 1];
  const int end0 = ft[j0];
  const bool act1 = (j0 + 1 < L);
  const int end1 = act1 ? ft[j0 + 1] : end0;
  nfloat4 acc00 = z, acc01 = z, acc02 = z;
  nfloat4 acc10 = z, acc11 = z, acc12 = z;
  for (int t = start0; t <= end1; ++t) {
    float2 wv = wpk[t];
    const nfloat4* xr = (const nfloat4*)(x + ((size_t)b * SS + t) * DD);
    nfloat4 v0 = xr[lane], v1 = xr[lane + 64], v2 = xr[lane + 128];
    if (t <= end0) { // row j0's segment
      float w = (j0 > 0 && t == start0) ? wv.y : wv.x;
      acc00 += w * v0; acc01 += w * v1; acc02 += w * v2;
    }
    if (act1 && t >= end0) { // row j0+1's segment starts at end0
      float w = (t == end0) ? wv.y : wv.x;
      acc10 += w * v0; acc11 += w * v1; acc12 += w * v2;
    }
  }
  __builtin_nontemporal_store(acc00, orow0 + lane);
  __builtin_nontemporal_store(acc01, orow0 + lane + 64);
  __builtin_nontemporal_store(acc02, orow0 + lane + 128);
  __builtin_nontemporal_store(acc10, orow1 + lane);
  __builtin_nontemporal_store(acc11, orow1 + lane + 64);
  __builtin_nontemporal_store(acc12, orow1 + lane + 128);
}

extern "C" void kernel_launch(void* const* d_in, const int* in_sizes, int n_in,
                              void* d_out, int out_size, void* d_ws, size_t ws_size,
                              hipStream_t stream) {
  const float* x      = (const float*)d_in[0]; // (B,S,D)
  const int*   lens   = (const int*)d_in[1];   // (B,)
  const float* conv_w = (const float*)d_in[2]; // (D,D,3)
  const float* conv_b = (const float*)d_in[3]; // (D,)
  const float* lin_w  = (const float*)d_in[4]; // (1,D)
  const float* lin_b  = (const float*)d_in[5]; // (1,)
  float* out = (float*)d_out;                  // B*S*D floats then B lens (as float)
  float* ws = (float*)d_ws;

  float* e0 = ws + E0_OFF;
  float* e1 = ws + E1_OFF;
  float* e2 = ws + E2_OFF;
  float2* wpk = (float2*)(ws + WPK_OFF);
  int* ft = (int*)(ws + FT_OFF);
  int* lenws = (int*)(ws + LEN_OFF);
  float* out_len = out + (size_t)NROW * DD;

  k1a_fold_part<<<NSLICE * 9, 256, 0, stream>>>(conv_w, lin_w, ws);
  k1r_fold_reduce<<<10, 256, 0, stream>>>(conv_b, lin_w, lin_b, ws);
  k2a_dots<<<NROW / 8, 256, 0, stream>>>(x, ws, lens, e0, e1, e2);
  k3_scan<<<BB, 256, 0, stream>>>(ws, lens, wpk, ft, lenws, out_len);
  k4_emit<<<NROW / 8, 256, 0, stream>>>(x, ws, out);
}